// Round 5
// baseline (16105.469 us; speedup 1.0000x reference)
//
#include <hip/hip_runtime.h>
#include <stdint.h>
#include <math.h>

// Problem constants
#define B_DIM 64
#define E_DIM 512
#define H_DIM 1024
#define V_DIM 32000
#define T_STEPS 31
#define GATES 4096          // 4*H
#define OUT_COLS 62         // 2*T
#define STOT 32             // K=1024 -> 32 k-steps of 32
#define NBLK 512            // persistent grid: 2 blocks/CU guaranteed
#define CBLK 500            // phase-C blocks (64 cols each)
#define PSTRIDE 512         // chunk-partial row stride

typedef _Float16 half8 __attribute__((ext_vector_type(8)));
typedef float floatx4 __attribute__((ext_vector_type(4)));

// ---------------- threefry2x32 (exact JAX reference) ----------------
__device__ __forceinline__ void tf_round(uint32_t& x0, uint32_t& x1, int r) {
  x0 += x1;
  x1 = (x1 << r) | (x1 >> (32 - r));
  x1 ^= x0;
}

__device__ __forceinline__ void threefry2x32(uint32_t k0, uint32_t k1,
                                             uint32_t& x0, uint32_t& x1) {
  uint32_t k2 = k0 ^ k1 ^ 0x1BD11BDAu;
  x0 += k0; x1 += k1;
  tf_round(x0,x1,13); tf_round(x0,x1,15); tf_round(x0,x1,26); tf_round(x0,x1,6);
  x0 += k1; x1 += k2 + 1u;
  tf_round(x0,x1,17); tf_round(x0,x1,29); tf_round(x0,x1,16); tf_round(x0,x1,24);
  x0 += k2; x1 += k0 + 2u;
  tf_round(x0,x1,13); tf_round(x0,x1,15); tf_round(x0,x1,26); tf_round(x0,x1,6);
  x0 += k0; x1 += k1 + 3u;
  tf_round(x0,x1,17); tf_round(x0,x1,29); tf_round(x0,x1,16); tf_round(x0,x1,24);
  x0 += k1; x1 += k2 + 4u;
  tf_round(x0,x1,13); tf_round(x0,x1,15); tf_round(x0,x1,26); tf_round(x0,x1,6);
  x0 += k2; x1 += k0 + 5u;
}

// JAX uniform->gumbel, partitionable counter mode (validated R1-R4)
__device__ __forceinline__ float gumbel_of(uint32_t k0, uint32_t k1, uint32_t ctr) {
  uint32_t y0 = 0u, y1 = ctr;
  threefry2x32(k0, k1, y0, y1);
  uint32_t bits = y0 ^ y1;
  float u = __uint_as_float((bits >> 9) | 0x3f800000u) - 1.0f;
  u = fmaxf(u, 1.17549435e-38f);
  return -logf(-logf(u));
}

// ---------------- small utility kernels ----------------
__global__ void zero_kernel(float* __restrict__ o, int n) {
  int i = blockIdx.x * blockDim.x + threadIdx.x;
  if (i < n) o[i] = 0.0f;
}

__global__ void copy_kernel(const float* __restrict__ a, float* __restrict__ o, int n) {
  int i = blockIdx.x * blockDim.x + threadIdx.x;
  if (i < n) o[i] = a[i];
}

// ---------------- weight repack (coalesced, LDS-staged) ----------------
// tile = 32 k-rows x 64 cols; grid (N/64, 32). fp32 (a [+ b]) -> f16 hi/lo
// B-fragments: chunk (nt, s) stored at ((nt*32+s)*2)*512, lo at +512.
__global__ __launch_bounds__(256)
void repack_w(const float* __restrict__ Wa, const float* __restrict__ Wb,
              _Float16* __restrict__ pk, int N) {
  __shared__ float tile[32][69];
  const int c0 = blockIdx.x * 64;
  const int r0 = blockIdx.y * 32;
  const int tid = threadIdx.x;
  const int rr = tid >> 4;
  const int cg = (tid & 15) * 4;
#pragma unroll
  for (int rep = 0; rep < 2; ++rep) {
    int row = rep * 16 + rr;
    float4 v = *(const float4*)(Wa + (size_t)(r0 + row) * N + c0 + cg);
    if (Wb) {
      float4 u = *(const float4*)(Wb + (size_t)(r0 + row) * N + c0 + cg);
      v.x += u.x; v.y += u.y; v.z += u.z; v.w += u.w;
    }
    tile[row][cg] = v.x; tile[row][cg+1] = v.y;
    tile[row][cg+2] = v.z; tile[row][cg+3] = v.w;
  }
  __syncthreads();
  const int w = tid >> 6, lane = tid & 63;
  const int quad = lane >> 4, lm = lane & 15;
  half8 hi, lo;
#pragma unroll
  for (int j = 0; j < 8; ++j) {
    float v = tile[quad * 8 + j][w * 16 + lm];
    _Float16 h = (_Float16)v;
    hi[j] = h;
    lo[j] = (_Float16)(v - (float)h);
  }
  int nt = blockIdx.x * 4 + w, s = blockIdx.y;
  _Float16* o = pk + ((size_t)(nt * 32 + s) * 2) * 512 + lane * 8;
  *(half8*)o = hi;
  *(half8*)(o + 512) = lo;
}

// ---------------- fp32 GEMM (encoder only, one-shot) ----------------
__global__ __launch_bounds__(256, 2)
void gemm64_kernel(const float* __restrict__ A, const float* __restrict__ W,
                   float* __restrict__ P, int K, int N) {
  const int vt = blockIdx.x;
  const int ks = blockIdx.y;
  const int kchunk = K / gridDim.y;
  const int kbase = ks * kchunk;
  const int v0 = vt * 256;

  __shared__ float As[32][68];
  __shared__ float Ws[32][256];

  float acc[8][8];
#pragma unroll
  for (int i = 0; i < 8; i++)
#pragma unroll
    for (int j = 0; j < 8; j++) acc[i][j] = 0.0f;

  const int tid = threadIdx.x;
  const int cg4 = (tid & 31) * 4;
  const int rg4 = (tid >> 5) * 4;

  for (int k0 = kbase; k0 < kbase + kchunk; k0 += 32) {
    __syncthreads();
    {
      int b  = tid >> 3;
      int f4 = tid & 7;
      const float* Ab = A + (size_t)b * K + k0 + f4 * 4;
      float4 a0 = *(const float4*)Ab;
      float4 a1 = *(const float4*)(Ab + (size_t)32 * K);
      int kk0 = f4 * 4;
      As[kk0+0][b] = a0.x; As[kk0+1][b] = a0.y; As[kk0+2][b] = a0.z; As[kk0+3][b] = a0.w;
      As[kk0+0][b+32] = a1.x; As[kk0+1][b+32] = a1.y; As[kk0+2][b+32] = a1.z; As[kk0+3][b+32] = a1.w;
    }
#pragma unroll
    for (int p = 0; p < 8; p++) {
      int idx = tid + p * 256;
      int row = idx >> 6, c4 = idx & 63;
      *(float4*)&Ws[row][c4 * 4] =
          *(const float4*)(W + (size_t)(k0 + row) * N + v0 + c4 * 4);
    }
    __syncthreads();

#pragma unroll 8
    for (int kk = 0; kk < 32; kk++) {
      float4 a0 = *(const float4*)&As[kk][rg4];
      float4 a1 = *(const float4*)&As[kk][32 + rg4];
      float4 w0 = *(const float4*)&Ws[kk][cg4];
      float4 w1 = *(const float4*)&Ws[kk][128 + cg4];
      float av[8] = {a0.x, a0.y, a0.z, a0.w, a1.x, a1.y, a1.z, a1.w};
      float wv[8] = {w0.x, w0.y, w0.z, w0.w, w1.x, w1.y, w1.z, w1.w};
#pragma unroll
      for (int i = 0; i < 8; i++)
#pragma unroll
        for (int j = 0; j < 8; j++)
          acc[i][j] = fmaf(av[i], wv[j], acc[i][j]);
    }
  }

  const size_t base = (size_t)ks * 64 * N;
#pragma unroll
  for (int i = 0; i < 8; i++) {
    int row = (i < 4) ? (rg4 + i) : (32 + rg4 + i - 4);
    float4 s0 = make_float4(acc[i][0], acc[i][1], acc[i][2], acc[i][3]);
    float4 s1 = make_float4(acc[i][4], acc[i][5], acc[i][6], acc[i][7]);
    *(float4*)(P + base + (size_t)row * N + v0 + cg4) = s0;
    *(float4*)(P + base + (size_t)row * N + v0 + 128 + cg4) = s1;
  }
}

// ---------------- LSTM gate fusion (encoder epilogue) ----------------
__global__ void gates_kernel(const float* __restrict__ zp, int ksplit,
                             const float* __restrict__ bias,
                             const float* __restrict__ c_in,
                             float* __restrict__ h_out, float* __restrict__ c_out,
                             _Float16* __restrict__ hpk) {
  int tid = blockIdx.x * blockDim.x + threadIdx.x;
  if (tid >= B_DIM * H_DIM) return;
  int b = tid >> 10, j = tid & 1023;
  float zi = bias[j], zf = bias[j + 1024], zg = bias[j + 2048], zo = bias[j + 3072];
  const float* Pb = zp + (size_t)b * GATES;
  for (int p = 0; p < ksplit; p++) {
    const float* P = Pb + (size_t)p * B_DIM * GATES;
    zi += P[j]; zf += P[j + 1024]; zg += P[j + 2048]; zo += P[j + 3072];
  }
  float cp = c_in ? c_in[tid] : 0.0f;
  float si = 1.0f / (1.0f + expf(-zi));
  float sf = 1.0f / (1.0f + expf(-zf));
  float so = 1.0f / (1.0f + expf(-zo));
  float c = sf * cp + si * zg;
  c_out[tid] = c;
  float hv = so * c;
  h_out[tid] = hv;

  int mt = b >> 4, lm = b & 15;
  int s = j >> 5, quad = (j >> 3) & 3, jj = j & 7;
  size_t off = ((size_t)(mt * 32 + s) * 2) * 512 + (size_t)(quad * 16 + lm) * 8 + jj;
  _Float16 hh = (_Float16)hv;
  hpk[off] = hh;
  hpk[off + 512] = (_Float16)(hv - (float)hh);
}

// ---------------- device-wide barrier (validated R4) ----------------
__device__ __forceinline__ void grid_barrier(int* bar) {
  __syncthreads();
  if (threadIdx.x == 0) {
    __threadfence();
    int g = __hip_atomic_load(&bar[1], __ATOMIC_RELAXED, __HIP_MEMORY_SCOPE_AGENT);
    int arrived = __hip_atomic_fetch_add(&bar[0], 1, __ATOMIC_ACQ_REL,
                                         __HIP_MEMORY_SCOPE_AGENT);
    if (arrived == (int)gridDim.x - 1) {
      __hip_atomic_store(&bar[0], 0, __ATOMIC_RELAXED, __HIP_MEMORY_SCOPE_AGENT);
      __hip_atomic_fetch_add(&bar[1], 1, __ATOMIC_RELEASE, __HIP_MEMORY_SCOPE_AGENT);
    } else {
      while (__hip_atomic_load(&bar[1], __ATOMIC_ACQUIRE,
                               __HIP_MEMORY_SCOPE_AGENT) == g)
        __builtin_amdgcn_s_sleep(1);
    }
    __threadfence();
  }
  __syncthreads();
}

// ---------------- fragment helpers (phase A) ----------------
__device__ __forceinline__ void loadA4(const half8* Ap, int s, int lane,
                                       half8 (&A)[4][2]) {
#pragma unroll
  for (int mt = 0; mt < 4; ++mt) {
    const half8* ap = Ap + ((size_t)(mt * 32 + s) * 2) * 64 + lane;
    A[mt][0] = ap[0];
    A[mt][1] = ap[64];
  }
}

__device__ __forceinline__ void loadB1(const half8* Wp, int ntA, int s, int lane,
                                       half8 (&B)[2]) {
  const half8* bp = Wp + ((size_t)(ntA * 32 + s) * 2) * 64 + lane;
  B[0] = bp[0];
  B[1] = bp[64];
}

__device__ __forceinline__ void mm1(floatx4 (&acc)[4], half8 (&A)[4][2],
                                    half8 (&B)[2]) {
#pragma unroll
  for (int mt = 0; mt < 4; ++mt) {
    acc[mt] = __builtin_amdgcn_mfma_f32_16x16x32_f16(A[mt][0], B[0], acc[mt], 0, 0, 0);
    acc[mt] = __builtin_amdgcn_mfma_f32_16x16x32_f16(A[mt][1], B[0], acc[mt], 0, 0, 0);
    acc[mt] = __builtin_amdgcn_mfma_f32_16x16x32_f16(A[mt][0], B[1], acc[mt], 0, 0, 0);
  }
}

// ---------------- phase A: state GEMM + gates, fused (blocks 64..127) --------
// block jt owns hidden cols jt*16..+15; wave w computes gate w's 64x16 z-tile.
__device__ __forceinline__ void phaseA(const half8* Ap, const half8* W2,
                                       const float* b2, float* c, float* h,
                                       _Float16* hout, float* smem, int jt) {
  const int w = threadIdx.x >> 6, lane = threadIdx.x & 63;
  const int quad = lane >> 4, lm = lane & 15;
  const int ntA = w * 64 + jt;            // col = w*1024 + jt*16

  floatx4 acc[4] = {};
  half8 a0[4][2], a1[4][2], b0[2], b1[2];

  loadA4(Ap, 0, lane, a0);
  loadB1(W2, ntA, 0, lane, b0);
  for (int s = 0; s < STOT; s += 2) {
    loadA4(Ap, s + 1, lane, a1);
    loadB1(W2, ntA, s + 1, lane, b1);
    mm1(acc, a0, b0);
    if (s + 2 < STOT) {
      loadA4(Ap, s + 2, lane, a0);
      loadB1(W2, ntA, s + 2, lane, b0);
    }
    mm1(acc, a1, b1);
  }

#pragma unroll
  for (int mt = 0; mt < 4; ++mt)
#pragma unroll
    for (int r = 0; r < 4; ++r) {
      int row = mt * 16 + quad * 4 + r;
      smem[w * 1088 + row * 17 + lm] = acc[mt][r];
    }
  __syncthreads();

  for (int e = threadIdx.x; e < 1024; e += 256) {
    int row = e >> 4, lmj = e & 15;
    int j = jt * 16 + lmj;
    float zi = smem[0 * 1088 + row * 17 + lmj] + b2[j];
    float zf = smem[1 * 1088 + row * 17 + lmj] + b2[j + 1024];
    float zg = smem[2 * 1088 + row * 17 + lmj] + b2[j + 2048];
    float zo = smem[3 * 1088 + row * 17 + lmj] + b2[j + 3072];
    float cp = c[row * 1024 + j];
    float si = 1.0f / (1.0f + expf(-zi));
    float sf = 1.0f / (1.0f + expf(-zf));
    float so = 1.0f / (1.0f + expf(-zo));
    float cn = sf * cp + si * zg;
    c[row * 1024 + j] = cn;
    float hv = so * cn;
    h[row * 1024 + j] = hv;
    int mt = row >> 4, lmr = row & 15;
    int sC = j >> 5, qd = (j >> 3) & 3, jj = j & 7;
    size_t off = ((size_t)(mt * 32 + sC) * 2) * 512 + (size_t)(qd * 16 + lmr) * 8 + jj;
    _Float16 hh = (_Float16)hv;
    hout[off] = hh;
    hout[off + 512] = (_Float16)(hv - (float)hh);
  }
  __syncthreads();
}

// ---------------- phase C: logits GEMM + fused sampling partials -------------
// blocks 0..499; block cb owns cols cb*64..+63; wave w owns rows w*16..+15
// (mt = w) and all 4 nt. Partials are wave-private per row -> direct store.
__device__ __forceinline__ void phaseC(const half8* Ap, const half8* Wd,
                                       const float* bd, int t,
                                       float* pm, float* ps, float* pt2,
                                       float* pbv, float* pbl, int* pbi) {
  const int cb = blockIdx.x;
  const int w = threadIdx.x >> 6, lane = threadIdx.x & 63;
  const int quad = lane >> 4, lm = lane & 15;
  const int mt = w;
  const int c0 = cb * 64;

  floatx4 acc[4] = {};
  half8 a0[2], a1[2], b0[4][2], b1[4][2];

#define LOAD_A1(s_, A_)                                                     \
  {                                                                         \
    const half8* ap = Ap + ((size_t)(mt * 32 + (s_)) * 2) * 64 + lane;      \
    A_[0] = ap[0];                                                          \
    A_[1] = ap[64];                                                         \
  }
#define LOAD_B4(s_, B_)                                                     \
  {                                                                         \
    _Pragma("unroll")                                                       \
    for (int nt = 0; nt < 4; ++nt) {                                        \
      const half8* bp =                                                     \
          Wd + ((size_t)((cb * 4 + nt) * 32 + (s_)) * 2) * 64 + lane;       \
      B_[nt][0] = bp[0];                                                    \
      B_[nt][1] = bp[64];                                                   \
    }                                                                       \
  }
#define MM4(A_, B_)                                                         \
  {                                                                         \
    _Pragma("unroll")                                                       \
    for (int nt = 0; nt < 4; ++nt) {                                        \
      acc[nt] = __builtin_amdgcn_mfma_f32_16x16x32_f16(A_[0], B_[nt][0], acc[nt], 0, 0, 0); \
      acc[nt] = __builtin_amdgcn_mfma_f32_16x16x32_f16(A_[1], B_[nt][0], acc[nt], 0, 0, 0); \
      acc[nt] = __builtin_amdgcn_mfma_f32_16x16x32_f16(A_[0], B_[nt][1], acc[nt], 0, 0, 0); \
    }                                                                       \
  }

  LOAD_A1(0, a0);
  LOAD_B4(0, b0);
  for (int s = 0; s < STOT; s += 2) {
    LOAD_A1(s + 1, a1);
    LOAD_B4(s + 1, b1);
    MM4(a0, b0);
    if (s + 2 < STOT) {
      LOAD_A1(s + 2, a0);
      LOAD_B4(s + 2, b0);
    }
    MM4(a1, b1);
  }
#undef LOAD_A1
#undef LOAD_B4
#undef MM4

  float bd4[4];
#pragma unroll
  for (int nt = 0; nt < 4; ++nt) bd4[nt] = bd[c0 + nt * 16 + lm];
  uint32_t tk0 = 0u, tk1 = (uint32_t)t;
  threefry2x32(0u, 1234u, tk0, tk1);

#pragma unroll
  for (int r = 0; r < 4; ++r) {
    int row = mt * 16 + quad * 4 + r;
    uint32_t base_ctr = (uint32_t)row * (uint32_t)V_DIM + (uint32_t)(c0 + lm);
    float l[4];
    float m = -INFINITY, bv = -INFINITY, bl = 0.0f;
    int bi = 0x7fffffff;
#pragma unroll
    for (int nt = 0; nt < 4; ++nt) {
      l[nt] = acc[nt][r] + bd4[nt];
      m = fmaxf(m, l[nt]);
      float g = gumbel_of(tk0, tk1, base_ctr + (uint32_t)(nt * 16));
      float v = l[nt] + g;
      if (v > bv) { bv = v; bi = c0 + nt * 16 + lm; bl = l[nt]; }
    }
#pragma unroll
    for (int off = 1; off <= 8; off <<= 1) m = fmaxf(m, __shfl_xor(m, off));
    float s_ = 0.0f, t2 = 0.0f;
#pragma unroll
    for (int nt = 0; nt < 4; ++nt) {
      float e = expf(l[nt] - m);
      s_ += e;
      t2 += e * l[nt];
    }
#pragma unroll
    for (int off = 1; off <= 8; off <<= 1) {
      s_ += __shfl_xor(s_, off);
      t2 += __shfl_xor(t2, off);
      float ob = __shfl_xor(bv, off);
      int   oi = __shfl_xor(bi, off);
      float ol = __shfl_xor(bl, off);
      if (ob > bv || (ob == bv && oi < bi)) { bv = ob; bi = oi; bl = ol; }
    }
    if (lm == 0) {
      int o = row * PSTRIDE + cb;
      pm[o] = m; ps[o] = s_; pt2[o] = t2; pbv[o] = bv; pbl[o] = bl; pbi[o] = bi;
    }
  }
}

// ---------------- phase D: reduce 500 chunk partials per row -----------------
__device__ __forceinline__ void phaseD(const float* pm, const float* ps,
                                       const float* pt2, const float* pbv,
                                       const float* pbl, const int* pbi,
                                       int t, float* out, float* smem) {
  const int row = blockIdx.x;
  const int tid = threadIdx.x;
  const int wave = tid >> 6, lane = tid & 63;
  const int o1 = row * PSTRIDE + tid;
  const bool v2 = (tid + 256) < CBLK;

  float m1 = pm[o1];
  float m2 = v2 ? pm[o1 + 256] : -INFINITY;
  float m = fmaxf(m1, m2);
  float M = m;
#pragma unroll
  for (int off = 32; off > 0; off >>= 1) M = fmaxf(M, __shfl_down(M, off));
  if (lane == 0) smem[wave] = M;
  __syncthreads();
  const float Mg = fmaxf(fmaxf(smem[0], smem[1]), fmaxf(smem[2], smem[3]));
  __syncthreads();

  float sc1 = expf(m1 - Mg);
  float s  = ps[o1] * sc1;
  float t2 = pt2[o1] * sc1;
  float bv = pbv[o1], bl = pbl[o1];
  int   bi = pbi[o1];
  if (v2) {
    float sc2 = expf(m2 - Mg);
    s  += ps[o1 + 256] * sc2;
    t2 += pt2[o1 + 256] * sc2;
    float ob = pbv[o1 + 256]; int oi = pbi[o1 + 256]; float ol = pbl[o1 + 256];
    if (ob > bv || (ob == bv && oi < bi)) { bv = ob; bi = oi; bl = ol; }
  }
#pragma unroll
  for (int off = 32; off > 0; off >>= 1) {
    s  += __shfl_down(s, off);
    t2 += __shfl_down(t2, off);
    float ob = __shfl_down(bv, off);
    int   oi = __shfl_down(bi, off);
    float ol = __shfl_down(bl, off);
    if (ob > bv || (ob == bv && oi < bi)) { bv = ob; bi = oi; bl = ol; }
  }
  if (lane == 0) {
    smem[4 + wave] = s;
    smem[8 + wave] = t2;
    smem[12 + wave] = bv;
    smem[16 + wave] = bl;
    smem[20 + wave] = __int_as_float(bi);
  }
  __syncthreads();
  if (tid == 0) {
    float S = 0.0f, T2 = 0.0f, Bv = -INFINITY, Bl = 0.0f;
    int BI = 0x7fffffff;
#pragma unroll
    for (int w4 = 0; w4 < 4; ++w4) {
      S += smem[4 + w4];
      T2 += smem[8 + w4];
      float ob = smem[12 + w4]; int oi = __float_as_int(smem[20 + w4]);
      float ol = smem[16 + w4];
      if (ob > Bv || (ob == Bv && oi < BI)) { Bv = ob; BI = oi; Bl = ol; }
    }
    float lse = Mg + logf(S);
    out[(size_t)row * OUT_COLS + t]        = (float)BI;    // msg
    out[3968 + (size_t)row * OUT_COLS + t] = Bl - lse;     // log_prob
    out[7936 + (size_t)row * OUT_COLS + t] = lse - T2 / S; // entropy
  }
  __syncthreads();
}

// ---------------- persistent decode kernel (512 blocks, 2/CU) ----------------
__global__ __launch_bounds__(256, 2)
void decode_kernel(const half8* __restrict__ W2pk, const half8* __restrict__ Wdpk,
                   const float* __restrict__ b2, const float* __restrict__ bd,
                   _Float16* __restrict__ hb0, _Float16* __restrict__ hb1,
                   float* __restrict__ h, float* __restrict__ c,
                   float* __restrict__ pm, float* __restrict__ ps,
                   float* __restrict__ pt2, float* __restrict__ pbv,
                   float* __restrict__ pbl, int* __restrict__ pbi,
                   float* __restrict__ out, int* __restrict__ bar) {
  __shared__ float smem[4352];   // phase A: 4*64*17 floats; phase D: 24 floats

#pragma unroll 1
  for (int t = 0; t < T_STEPS; ++t) {
    _Float16* hin  = (t & 1) ? hb1 : hb0;
    _Float16* hout = (t & 1) ? hb0 : hb1;
    if (blockIdx.x >= 64 && blockIdx.x < 128)
      phaseA((const half8*)hin, W2pk, b2, c, h, hout, smem, (int)blockIdx.x - 64);
    else if (t > 0 && blockIdx.x < 64)
      phaseD(pm, ps, pt2, pbv, pbl, pbi, t - 1, out, smem);
    grid_barrier(bar);
    if (blockIdx.x < CBLK)
      phaseC((const half8*)hout, Wdpk, bd, t, pm, ps, pt2, pbv, pbl, pbi);
    grid_barrier(bar);
  }
  if (blockIdx.x < 64)
    phaseD(pm, ps, pt2, pbv, pbl, pbi, T_STEPS - 1, out, smem);
}

// ---------------- launcher ----------------
extern "C" void kernel_launch(void* const* d_in, const int* in_sizes, int n_in,
                              void* d_out, int out_size, void* d_ws, size_t ws_size,
                              hipStream_t stream) {
  const float* inp = (const float*)d_in[0];
  const float* Wx1 = (const float*)d_in[1];
  // d_in[2] = Wh1: unused (encoder initial h == 0)
  const float* b1  = (const float*)d_in[3];
  const float* Wx2 = (const float*)d_in[4];
  const float* Wh2 = (const float*)d_in[5];
  const float* b2  = (const float*)d_in[6];
  const float* Wd  = (const float*)d_in[7];
  const float* bd  = (const float*)d_in[8];
  float* out = (float*)d_out;

  float* ws = (float*)d_ws;
  float* Wd_pk  = ws;                     // 32,768,000 floats
  float* W2_pk  = Wd_pk + 32768000;       //  4,194,304
  float* hb0f   = W2_pk + 4194304;        //     65,536
  float* hb1f   = hb0f + 65536;           //     65,536
  float* h      = hb1f + 65536;           //     65,536
  float* c      = h + 65536;              //     65,536
  float* zparts = c + 65536;              //  1,048,576 (encoder, 4 parts)
  float* pm     = zparts + 1048576;       //  64*512 = 32,768 each
  float* ps     = pm + 32768;
  float* pt2    = ps + 32768;
  float* pbv    = pt2 + 32768;
  float* pbl    = pbv + 32768;
  int*   pbi    = (int*)(pbl + 32768);
  int*   bar    = (int*)(pbi + 32768);    // 2 ints

  _Float16* hb0 = (_Float16*)hb0f;
  _Float16* hb1 = (_Float16*)hb1f;

  // one-time per call: weight repack (coalesced) + zero-init
  repack_w<<<dim3(V_DIM / 64, 32), 256, 0, stream>>>(Wd, nullptr,
                                                     (_Float16*)Wd_pk, V_DIM);
  repack_w<<<dim3(GATES / 64, 32), 256, 0, stream>>>(Wx2, Wh2,
                                                     (_Float16*)W2_pk, GATES);
  zero_kernel<<<47, 256, 0, stream>>>(out, 11904);
  zero_kernel<<<1, 64, 0, stream>>>((float*)bar, 2);

  // encoder: single step, zero initial state -> z = x@Wx1 + b1 (fp32)
  gemm64_kernel<<<dim3(16, 4), 256, 0, stream>>>(inp, Wx1, zparts, E_DIM, GATES);
  gates_kernel<<<256, 256, 0, stream>>>(zparts, 4, b1, nullptr, h, c, hb0);

  // entire 31-step decode loop in one persistent kernel (2 blocks/CU)
  decode_kernel<<<NBLK, 256, 0, stream>>>(
      (const half8*)W2_pk, (const half8*)Wd_pk, b2, bd, hb0, hb1, h, c,
      pm, ps, pt2, pbv, pbl, pbi, out, bar);

  copy_kernel<<<256, 256, 0, stream>>>(h, out + 11904, B_DIM * H_DIM);
}

// Round 7
// 3024.838 us; speedup vs baseline: 5.3244x; 5.3244x over previous
//
#include <hip/hip_runtime.h>
#include <stdint.h>
#include <math.h>

// Problem constants
#define B_DIM 64
#define E_DIM 512
#define H_DIM 1024
#define V_DIM 32000
#define T_STEPS 31
#define GATES 4096          // 4*H
#define OUT_COLS 62         // 2*T
#define STOT 32             // K=1024 -> 32 k-steps of 32
#define NBLK 256            // persistent grid: 1 block/CU
#define CBLK 250            // phase-C blocks (128 cols each)

typedef _Float16 half8 __attribute__((ext_vector_type(8)));
typedef float floatx4 __attribute__((ext_vector_type(4)));

// ---------------- threefry2x32 (exact JAX reference) ----------------
__device__ __forceinline__ void tf_round(uint32_t& x0, uint32_t& x1, int r) {
  x0 += x1;
  x1 = (x1 << r) | (x1 >> (32 - r));
  x1 ^= x0;
}

__device__ __forceinline__ void threefry2x32(uint32_t k0, uint32_t k1,
                                             uint32_t& x0, uint32_t& x1) {
  uint32_t k2 = k0 ^ k1 ^ 0x1BD11BDAu;
  x0 += k0; x1 += k1;
  tf_round(x0,x1,13); tf_round(x0,x1,15); tf_round(x0,x1,26); tf_round(x0,x1,6);
  x0 += k1; x1 += k2 + 1u;
  tf_round(x0,x1,17); tf_round(x0,x1,29); tf_round(x0,x1,16); tf_round(x0,x1,24);
  x0 += k2; x1 += k0 + 2u;
  tf_round(x0,x1,13); tf_round(x0,x1,15); tf_round(x0,x1,26); tf_round(x0,x1,6);
  x0 += k0; x1 += k1 + 3u;
  tf_round(x0,x1,17); tf_round(x0,x1,29); tf_round(x0,x1,16); tf_round(x0,x1,24);
  x0 += k1; x1 += k2 + 4u;
  tf_round(x0,x1,13); tf_round(x0,x1,15); tf_round(x0,x1,26); tf_round(x0,x1,6);
  x0 += k2; x1 += k0 + 5u;
}

// JAX uniform->gumbel, partitionable counter mode (validated R1-R5)
__device__ __forceinline__ float gumbel_of(uint32_t k0, uint32_t k1, uint32_t ctr) {
  uint32_t y0 = 0u, y1 = ctr;
  threefry2x32(k0, k1, y0, y1);
  uint32_t bits = y0 ^ y1;
  float u = __uint_as_float((bits >> 9) | 0x3f800000u) - 1.0f;
  u = fmaxf(u, 1.17549435e-38f);
  return -logf(-logf(u));
}

// ---------------- small utility kernels ----------------
__global__ void zero_kernel(float* __restrict__ o, int n) {
  int i = blockIdx.x * blockDim.x + threadIdx.x;
  if (i < n) o[i] = 0.0f;
}

__global__ void copy_kernel(const float* __restrict__ a, float* __restrict__ o, int n) {
  int i = blockIdx.x * blockDim.x + threadIdx.x;
  if (i < n) o[i] = a[i];
}

// ---------------- weight repack (coalesced, LDS-staged) ----------------
__global__ __launch_bounds__(256)
void repack_w(const float* __restrict__ Wa, const float* __restrict__ Wb,
              _Float16* __restrict__ pk, int N) {
  __shared__ float tile[32][69];
  const int c0 = blockIdx.x * 64;
  const int r0 = blockIdx.y * 32;
  const int tid = threadIdx.x;
  const int rr = tid >> 4;
  const int cg = (tid & 15) * 4;
#pragma unroll
  for (int rep = 0; rep < 2; ++rep) {
    int row = rep * 16 + rr;
    float4 v = *(const float4*)(Wa + (size_t)(r0 + row) * N + c0 + cg);
    if (Wb) {
      float4 u = *(const float4*)(Wb + (size_t)(r0 + row) * N + c0 + cg);
      v.x += u.x; v.y += u.y; v.z += u.z; v.w += u.w;
    }
    tile[row][cg] = v.x; tile[row][cg+1] = v.y;
    tile[row][cg+2] = v.z; tile[row][cg+3] = v.w;
  }
  __syncthreads();
  const int w = tid >> 6, lane = tid & 63;
  const int quad = lane >> 4, lm = lane & 15;
  half8 hi, lo;
#pragma unroll
  for (int j = 0; j < 8; ++j) {
    float v = tile[quad * 8 + j][w * 16 + lm];
    _Float16 h = (_Float16)v;
    hi[j] = h;
    lo[j] = (_Float16)(v - (float)h);
  }
  int nt = blockIdx.x * 4 + w, s = blockIdx.y;
  _Float16* o = pk + ((size_t)(nt * 32 + s) * 2) * 512 + lane * 8;
  *(half8*)o = hi;
  *(half8*)(o + 512) = lo;
}

// ---------------- fp32 GEMM (encoder only, one-shot) ----------------
__global__ __launch_bounds__(256, 2)
void gemm64_kernel(const float* __restrict__ A, const float* __restrict__ W,
                   float* __restrict__ P, int K, int N) {
  const int vt = blockIdx.x;
  const int ks = blockIdx.y;
  const int kchunk = K / gridDim.y;
  const int kbase = ks * kchunk;
  const int v0 = vt * 256;

  __shared__ float As[32][68];
  __shared__ float Ws[32][256];

  float acc[8][8];
#pragma unroll
  for (int i = 0; i < 8; i++)
#pragma unroll
    for (int j = 0; j < 8; j++) acc[i][j] = 0.0f;

  const int tid = threadIdx.x;
  const int cg4 = (tid & 31) * 4;
  const int rg4 = (tid >> 5) * 4;

  for (int k0 = kbase; k0 < kbase + kchunk; k0 += 32) {
    __syncthreads();
    {
      int b  = tid >> 3;
      int f4 = tid & 7;
      const float* Ab = A + (size_t)b * K + k0 + f4 * 4;
      float4 a0 = *(const float4*)Ab;
      float4 a1 = *(const float4*)(Ab + (size_t)32 * K);
      int kk0 = f4 * 4;
      As[kk0+0][b] = a0.x; As[kk0+1][b] = a0.y; As[kk0+2][b] = a0.z; As[kk0+3][b] = a0.w;
      As[kk0+0][b+32] = a1.x; As[kk0+1][b+32] = a1.y; As[kk0+2][b+32] = a1.z; As[kk0+3][b+32] = a1.w;
    }
#pragma unroll
    for (int p = 0; p < 8; p++) {
      int idx = tid + p * 256;
      int row = idx >> 6, c4 = idx & 63;
      *(float4*)&Ws[row][c4 * 4] =
          *(const float4*)(W + (size_t)(k0 + row) * N + v0 + c4 * 4);
    }
    __syncthreads();

#pragma unroll 8
    for (int kk = 0; kk < 32; kk++) {
      float4 a0 = *(const float4*)&As[kk][rg4];
      float4 a1 = *(const float4*)&As[kk][32 + rg4];
      float4 w0 = *(const float4*)&Ws[kk][cg4];
      float4 w1 = *(const float4*)&Ws[kk][128 + cg4];
      float av[8] = {a0.x, a0.y, a0.z, a0.w, a1.x, a1.y, a1.z, a1.w};
      float wv[8] = {w0.x, w0.y, w0.z, w0.w, w1.x, w1.y, w1.z, w1.w};
#pragma unroll
      for (int i = 0; i < 8; i++)
#pragma unroll
        for (int j = 0; j < 8; j++)
          acc[i][j] = fmaf(av[i], wv[j], acc[i][j]);
    }
  }

  const size_t base = (size_t)ks * 64 * N;
#pragma unroll
  for (int i = 0; i < 8; i++) {
    int row = (i < 4) ? (rg4 + i) : (32 + rg4 + i - 4);
    float4 s0 = make_float4(acc[i][0], acc[i][1], acc[i][2], acc[i][3]);
    float4 s1 = make_float4(acc[i][4], acc[i][5], acc[i][6], acc[i][7]);
    *(float4*)(P + base + (size_t)row * N + v0 + cg4) = s0;
    *(float4*)(P + base + (size_t)row * N + v0 + 128 + cg4) = s1;
  }
}

// ---------------- LSTM gate fusion (encoder epilogue) ----------------
__global__ void gates_kernel(const float* __restrict__ zp, int ksplit,
                             const float* __restrict__ bias,
                             const float* __restrict__ c_in,
                             float* __restrict__ h_out, float* __restrict__ c_out,
                             _Float16* __restrict__ hpk) {
  int tid = blockIdx.x * blockDim.x + threadIdx.x;
  if (tid >= B_DIM * H_DIM) return;
  int b = tid >> 10, j = tid & 1023;
  float zi = bias[j], zf = bias[j + 1024], zg = bias[j + 2048], zo = bias[j + 3072];
  const float* Pb = zp + (size_t)b * GATES;
  for (int p = 0; p < ksplit; p++) {
    const float* P = Pb + (size_t)p * B_DIM * GATES;
    zi += P[j]; zf += P[j + 1024]; zg += P[j + 2048]; zo += P[j + 3072];
  }
  float cp = c_in ? c_in[tid] : 0.0f;
  float si = 1.0f / (1.0f + expf(-zi));
  float sf = 1.0f / (1.0f + expf(-zf));
  float so = 1.0f / (1.0f + expf(-zo));
  float c = sf * cp + si * zg;
  c_out[tid] = c;
  float hv = so * c;
  h_out[tid] = hv;

  int mt = b >> 4, lm = b & 15;
  int s = j >> 5, quad = (j >> 3) & 3, jj = j & 7;
  size_t off = ((size_t)(mt * 32 + s) * 2) * 512 + (size_t)(quad * 16 + lm) * 8 + jj;
  _Float16 hh = (_Float16)hv;
  hpk[off] = hh;
  hpk[off + 512] = (_Float16)(hv - (float)hh);
}

// ---------------- device-wide barrier: RELAXED spin, ONE fence pair ---------
// The R4/R5 version did an agent-scope ACQUIRE load per poll -> buffer_inv
// (full L1+L2 invalidate) every ~100 cycles per spinner, poisoning all cache
// residency on every XCD hosting a spinner. Fixed: relaxed polling; exactly
// one release fence on entry and one acquire fence on exit.
__device__ __forceinline__ void grid_barrier(int* bar) {
  __syncthreads();
  if (threadIdx.x == 0) {
    __builtin_amdgcn_fence(__ATOMIC_RELEASE, "agent");   // publish our writes
    int g = __hip_atomic_load(&bar[1], __ATOMIC_RELAXED, __HIP_MEMORY_SCOPE_AGENT);
    int arrived = __hip_atomic_fetch_add(&bar[0], 1, __ATOMIC_RELAXED,
                                         __HIP_MEMORY_SCOPE_AGENT);
    if (arrived == (int)gridDim.x - 1) {
      __hip_atomic_store(&bar[0], 0, __ATOMIC_RELAXED, __HIP_MEMORY_SCOPE_AGENT);
      // release store: counter reset ordered before generation publish
      __hip_atomic_store(&bar[1], g + 1, __ATOMIC_RELEASE, __HIP_MEMORY_SCOPE_AGENT);
    } else {
      while (__hip_atomic_load(&bar[1], __ATOMIC_RELAXED,
                               __HIP_MEMORY_SCOPE_AGENT) == g)
        __builtin_amdgcn_s_sleep(4);
    }
    __builtin_amdgcn_fence(__ATOMIC_ACQUIRE, "agent");   // invalidate once
  }
  __syncthreads();
}

// ---------------- fragment helpers ----------------
__device__ __forceinline__ void loadA4(const half8* Ap, int s, int lane,
                                       half8 (&A)[4][2]) {
#pragma unroll
  for (int mt = 0; mt < 4; ++mt) {
    const half8* ap = Ap + ((size_t)(mt * 32 + s) * 2) * 64 + lane;
    A[mt][0] = ap[0];
    A[mt][1] = ap[64];
  }
}

__device__ __forceinline__ void loadB2(const half8* Wp, int nt0, int s, int lane,
                                       half8 (&B)[2][2]) {
#pragma unroll
  for (int j = 0; j < 2; ++j) {
    const half8* bp = Wp + ((size_t)((nt0 + j) * 32 + s) * 2) * 64 + lane;
    B[j][0] = bp[0];
    B[j][1] = bp[64];
  }
}

__device__ __forceinline__ void loadB1(const half8* Wp, int ntA, int s, int lane,
                                       half8 (&B)[2]) {
  const half8* bp = Wp + ((size_t)(ntA * 32 + s) * 2) * 64 + lane;
  B[0] = bp[0];
  B[1] = bp[64];
}

__device__ __forceinline__ void mm2(floatx4 (&acc)[4][2], half8 (&A)[4][2],
                                    half8 (&B)[2][2]) {
#pragma unroll
  for (int mt = 0; mt < 4; ++mt)
#pragma unroll
    for (int j = 0; j < 2; ++j) {
      acc[mt][j] = __builtin_amdgcn_mfma_f32_16x16x32_f16(A[mt][0], B[j][0], acc[mt][j], 0, 0, 0);
      acc[mt][j] = __builtin_amdgcn_mfma_f32_16x16x32_f16(A[mt][1], B[j][0], acc[mt][j], 0, 0, 0);
      acc[mt][j] = __builtin_amdgcn_mfma_f32_16x16x32_f16(A[mt][0], B[j][1], acc[mt][j], 0, 0, 0);
    }
}

__device__ __forceinline__ void mm1(floatx4 (&acc)[4], half8 (&A)[4][2],
                                    half8 (&B)[2]) {
#pragma unroll
  for (int mt = 0; mt < 4; ++mt) {
    acc[mt] = __builtin_amdgcn_mfma_f32_16x16x32_f16(A[mt][0], B[0], acc[mt], 0, 0, 0);
    acc[mt] = __builtin_amdgcn_mfma_f32_16x16x32_f16(A[mt][1], B[0], acc[mt], 0, 0, 0);
    acc[mt] = __builtin_amdgcn_mfma_f32_16x16x32_f16(A[mt][0], B[1], acc[mt], 0, 0, 0);
  }
}

// ---------------- phase A: state GEMM + gates, fused (blocks 64..127) --------
__device__ __forceinline__ void phaseA(const half8* Ap, const half8* W2,
                                       const float* b2, float* c, float* h,
                                       _Float16* hout, float* smem, int jt) {
  const int w = threadIdx.x >> 6, lane = threadIdx.x & 63;
  const int quad = lane >> 4, lm = lane & 15;
  const int ntA = w * 64 + jt;            // col = w*1024 + jt*16

  floatx4 acc[4] = {};
  half8 a0[4][2], a1[4][2], b0[2], b1[2];

  loadA4(Ap, 0, lane, a0);
  loadB1(W2, ntA, 0, lane, b0);
  for (int s = 0; s < STOT; s += 2) {
    loadA4(Ap, s + 1, lane, a1);
    loadB1(W2, ntA, s + 1, lane, b1);
    mm1(acc, a0, b0);
    if (s + 2 < STOT) {
      loadA4(Ap, s + 2, lane, a0);
      loadB1(W2, ntA, s + 2, lane, b0);
    }
    mm1(acc, a1, b1);
  }

#pragma unroll
  for (int mt = 0; mt < 4; ++mt)
#pragma unroll
    for (int r = 0; r < 4; ++r) {
      int row = mt * 16 + quad * 4 + r;
      smem[w * 1088 + row * 17 + lm] = acc[mt][r];
    }
  __syncthreads();

  for (int e = threadIdx.x; e < 1024; e += 256) {
    int row = e >> 4, lmj = e & 15;
    int j = jt * 16 + lmj;
    float zi = smem[0 * 1088 + row * 17 + lmj] + b2[j];
    float zf = smem[1 * 1088 + row * 17 + lmj] + b2[j + 1024];
    float zg = smem[2 * 1088 + row * 17 + lmj] + b2[j + 2048];
    float zo = smem[3 * 1088 + row * 17 + lmj] + b2[j + 3072];
    float cp = c[row * 1024 + j];
    float si = 1.0f / (1.0f + expf(-zi));
    float sf = 1.0f / (1.0f + expf(-zf));
    float so = 1.0f / (1.0f + expf(-zo));
    float cn = sf * cp + si * zg;
    c[row * 1024 + j] = cn;
    float hv = so * cn;
    h[row * 1024 + j] = hv;
    int mt = row >> 4, lmr = row & 15;
    int sC = j >> 5, qd = (j >> 3) & 3, jj = j & 7;
    size_t off = ((size_t)(mt * 32 + sC) * 2) * 512 + (size_t)(qd * 16 + lmr) * 8 + jj;
    _Float16 hh = (_Float16)hv;
    hout[off] = hh;
    hout[off + 512] = (_Float16)(hv - (float)hh);
  }
  __syncthreads();
}

// ---------------- phase C: logits GEMM + fused sampling partials -------------
// blocks 0..249; block cb owns cols cb*128..+127; wave w -> nt {cb*8+2w, +1}.
// Partial record per (row, cb): 8 floats {m, s, t2, bv, bl, bi, 0, 0}.
__device__ __forceinline__ void phaseC(const half8* Ap, const half8* Wd,
                                       const float* bd, int t,
                                       float* part, float* smem) {
  const int cb = blockIdx.x;
  const int w = threadIdx.x >> 6, lane = threadIdx.x & 63;
  const int quad = lane >> 4, lm = lane & 15;
  const int nt0 = cb * 8 + w * 2;

  floatx4 acc[4][2] = {};
  half8 a0[4][2], a1[4][2], b0[2][2], b1[2][2];

  loadA4(Ap, 0, lane, a0);
  loadB2(Wd, nt0, 0, lane, b0);
  for (int s = 0; s < STOT; s += 2) {
    loadA4(Ap, s + 1, lane, a1);
    loadB2(Wd, nt0, s + 1, lane, b1);
    mm2(acc, a0, b0);
    if (s + 2 < STOT) {
      loadA4(Ap, s + 2, lane, a0);
      loadB2(Wd, nt0, s + 2, lane, b0);
    }
    mm2(acc, a1, b1);
  }

  const int c0 = cb * 128 + w * 32 + lm;
  const float bd0 = bd[c0];
  const float bd1 = bd[c0 + 16];
  uint32_t tk0 = 0u, tk1 = (uint32_t)t;
  threefry2x32(0u, 1234u, tk0, tk1);

#pragma unroll
  for (int mt = 0; mt < 4; ++mt) {
#pragma unroll
    for (int r = 0; r < 4; ++r) {
      int row = mt * 16 + quad * 4 + r;
      float l0 = acc[mt][0][r] + bd0;
      float l1 = acc[mt][1][r] + bd1;
      uint32_t ctr = (uint32_t)row * (uint32_t)V_DIM + (uint32_t)c0;
      float g0 = gumbel_of(tk0, tk1, ctr);
      float g1 = gumbel_of(tk0, tk1, ctr + 16u);
      float v0 = l0 + g0, v1 = l1 + g1;
      float bv, bl; int bi;
      if (v1 > v0) { bv = v1; bi = c0 + 16; bl = l1; }
      else         { bv = v0; bi = c0;      bl = l0; }
      float m = fmaxf(l0, l1);
#pragma unroll
      for (int off = 1; off <= 8; off <<= 1) m = fmaxf(m, __shfl_xor(m, off));
      float e0 = expf(l0 - m), e1 = expf(l1 - m);
      float s_ = e0 + e1;
      float t2 = e0 * l0 + e1 * l1;
#pragma unroll
      for (int off = 1; off <= 8; off <<= 1) {
        s_ += __shfl_xor(s_, off);
        t2 += __shfl_xor(t2, off);
        float ob = __shfl_xor(bv, off);
        int   oi = __shfl_xor(bi, off);
        float ol = __shfl_xor(bl, off);
        if (ob > bv || (ob == bv && oi < bi)) { bv = ob; bi = oi; bl = ol; }
      }
      if (lm == 0) {
        float* P = smem + (size_t)(w * 64 + row) * 6;
        P[0] = m; P[1] = s_; P[2] = t2; P[3] = bv; P[4] = bl;
        P[5] = __int_as_float(bi);
      }
    }
  }
  __syncthreads();
  if (threadIdx.x < 64) {
    int row = threadIdx.x;
    float M = -INFINITY;
#pragma unroll
    for (int w4 = 0; w4 < 4; ++w4)
      M = fmaxf(M, smem[(size_t)(w4 * 64 + row) * 6 + 0]);
    float S = 0.0f, T2 = 0.0f, Bv = -INFINITY, Bl = 0.0f;
    int BI = 0x7fffffff;
#pragma unroll
    for (int w4 = 0; w4 < 4; ++w4) {
      const float* P = smem + (size_t)(w4 * 64 + row) * 6;
      float sc = expf(P[0] - M);
      S  += P[1] * sc;
      T2 += P[2] * sc;
      float ob = P[3]; int oi = __float_as_int(P[5]); float ol = P[4];
      if (ob > Bv || (ob == Bv && oi < BI)) { Bv = ob; BI = oi; Bl = ol; }
    }
    float* g = part + ((size_t)row * 256 + cb) * 8;
    *(float4*)g = make_float4(M, S, T2, Bv);
    *(float4*)(g + 4) = make_float4(Bl, __int_as_float(BI), 0.0f, 0.0f);
  }
  __syncthreads();
}

// ---------------- phase D: reduce 250 chunk records per row ------------------
__device__ __forceinline__ void phaseD(const float* part, int t,
                                       float* out, float* smem) {
  const int row = blockIdx.x;
  const int tid = threadIdx.x;
  const int wave = tid >> 6, lane = tid & 63;
  const bool valid = tid < CBLK;
  const float* rec = part + ((size_t)row * 256 + tid) * 8;

  float m  = valid ? rec[0] : -INFINITY;
  float s0 = valid ? rec[1] : 0.0f;
  float t0 = valid ? rec[2] : 0.0f;
  float bv = valid ? rec[3] : -INFINITY;
  float bl = valid ? rec[4] : 0.0f;
  int   bi = valid ? __float_as_int(rec[5]) : 0x7fffffff;

  float M = m;
#pragma unroll
  for (int off = 32; off > 0; off >>= 1) M = fmaxf(M, __shfl_down(M, off));
  if (lane == 0) smem[wave] = M;
  __syncthreads();
  const float Mg = fmaxf(fmaxf(smem[0], smem[1]), fmaxf(smem[2], smem[3]));
  __syncthreads();

  float sc = valid ? expf(m - Mg) : 0.0f;
  float s  = s0 * sc;
  float t2 = t0 * sc;
#pragma unroll
  for (int off = 32; off > 0; off >>= 1) {
    s  += __shfl_down(s, off);
    t2 += __shfl_down(t2, off);
    float ob = __shfl_down(bv, off);
    int   oi = __shfl_down(bi, off);
    float ol = __shfl_down(bl, off);
    if (ob > bv || (ob == bv && oi < bi)) { bv = ob; bi = oi; bl = ol; }
  }
  if (lane == 0) {
    smem[4 + wave] = s;
    smem[8 + wave] = t2;
    smem[12 + wave] = bv;
    smem[16 + wave] = bl;
    smem[20 + wave] = __int_as_float(bi);
  }
  __syncthreads();
  if (tid == 0) {
    float S = 0.0f, T2 = 0.0f, Bv = -INFINITY, Bl = 0.0f;
    int BI = 0x7fffffff;
#pragma unroll
    for (int w4 = 0; w4 < 4; ++w4) {
      S += smem[4 + w4];
      T2 += smem[8 + w4];
      float ob = smem[12 + w4]; int oi = __float_as_int(smem[20 + w4]);
      float ol = smem[16 + w4];
      if (ob > Bv || (ob == Bv && oi < BI)) { Bv = ob; BI = oi; Bl = ol; }
    }
    float lse = Mg + logf(S);
    out[(size_t)row * OUT_COLS + t]        = (float)BI;    // msg
    out[3968 + (size_t)row * OUT_COLS + t] = Bl - lse;     // log_prob
    out[7936 + (size_t)row * OUT_COLS + t] = lse - T2 / S; // entropy
  }
  __syncthreads();
}

// ---------------- persistent decode kernel (256 blocks, 1/CU) ----------------
__global__ __launch_bounds__(256, 1)
void decode_kernel(const half8* __restrict__ W2pk, const half8* __restrict__ Wdpk,
                   const float* __restrict__ b2, const float* __restrict__ bd,
                   _Float16* __restrict__ hb0, _Float16* __restrict__ hb1,
                   float* __restrict__ h, float* __restrict__ c,
                   float* __restrict__ part,
                   float* __restrict__ out, int* __restrict__ bar) {
  __shared__ float smem[4352];   // A: 4*64*17; C: 4*64*6; D: 24

#pragma unroll 1
  for (int t = 0; t < T_STEPS; ++t) {
    _Float16* hin  = (t & 1) ? hb1 : hb0;
    _Float16* hout = (t & 1) ? hb0 : hb1;
    if (blockIdx.x >= 64 && blockIdx.x < 128)
      phaseA((const half8*)hin, W2pk, b2, c, h, hout, smem, (int)blockIdx.x - 64);
    else if (t > 0 && blockIdx.x < 64)
      phaseD(part, t - 1, out, smem);
    grid_barrier(bar);
    if (blockIdx.x < CBLK)
      phaseC((const half8*)hout, Wdpk, bd, t, part, smem);
    grid_barrier(bar);
  }
  if (blockIdx.x < 64)
    phaseD(part, T_STEPS - 1, out, smem);
}

// ---------------- launcher ----------------
extern "C" void kernel_launch(void* const* d_in, const int* in_sizes, int n_in,
                              void* d_out, int out_size, void* d_ws, size_t ws_size,
                              hipStream_t stream) {
  const float* inp = (const float*)d_in[0];
  const float* Wx1 = (const float*)d_in[1];
  // d_in[2] = Wh1: unused (encoder initial h == 0)
  const float* b1  = (const float*)d_in[3];
  const float* Wx2 = (const float*)d_in[4];
  const float* Wh2 = (const float*)d_in[5];
  const float* b2  = (const float*)d_in[6];
  const float* Wd  = (const float*)d_in[7];
  const float* bd  = (const float*)d_in[8];
  float* out = (float*)d_out;

  float* ws = (float*)d_ws;
  float* Wd_pk  = ws;                     // 32,768,000 floats
  float* W2_pk  = Wd_pk + 32768000;       //  4,194,304
  float* hb0f   = W2_pk + 4194304;        //     65,536
  float* hb1f   = hb0f + 65536;           //     65,536
  float* h      = hb1f + 65536;           //     65,536
  float* c      = h + 65536;              //     65,536
  float* zparts = c + 65536;              //  1,048,576 (encoder, 4 parts)
  float* part   = zparts + 1048576;       //  64*256*8 = 131,072
  int*   bar    = (int*)(part + 131072);  // 2 ints

  _Float16* hb0 = (_Float16*)hb0f;
  _Float16* hb1 = (_Float16*)hb1f;

  // one-time per call: weight repack (coalesced) + zero-init
  repack_w<<<dim3(V_DIM / 64, 32), 256, 0, stream>>>(Wd, nullptr,
                                                     (_Float16*)Wd_pk, V_DIM);
  repack_w<<<dim3(GATES / 64, 32), 256, 0, stream>>>(Wx2, Wh2,
                                                     (_Float16*)W2_pk, GATES);
  zero_kernel<<<47, 256, 0, stream>>>(out, 11904);
  zero_kernel<<<1, 64, 0, stream>>>((float*)bar, 2);

  // encoder: single step, zero initial state -> z = x@Wx1 + b1 (fp32)
  gemm64_kernel<<<dim3(16, 4), 256, 0, stream>>>(inp, Wx1, zparts, E_DIM, GATES);
  gates_kernel<<<256, 256, 0, stream>>>(zparts, 4, b1, nullptr, h, c, hb0);

  // entire 31-step decode loop in one persistent kernel
  decode_kernel<<<NBLK, 256, 0, stream>>>(
      (const half8*)W2_pk, (const half8*)Wd_pk, b2, bd, hb0, hb1, h, c,
      part, out, bar);

  copy_kernel<<<256, 256, 0, stream>>>(h, out + 11904, B_DIM * H_DIM);
}